// Round 6
// baseline (504.610 us; speedup 1.0000x reference)
//
#include <hip/hip_runtime.h>

#define EMB 64
#define BUCKET_SHIFT 10          // bucket = row >> 10  (~147 buckets, 64KB windows)
#define EPB 4096                 // edges per block in build_pass1

// native clang vector types for nontemporal builtins (ABI-compatible with
// float4 / int2 — HIP_vector_type is rejected by the builtin)
typedef float nt_f4 __attribute__((ext_vector_type(4)));
typedef int   nt_i2 __attribute__((ext_vector_type(2)));

// Copy user_emb ++ item_emb into cur buffer AND into acc (d_out).
__global__ void concat_init(const float4* __restrict__ ue,
                            const float4* __restrict__ ie,
                            float4* __restrict__ cur,
                            float4* __restrict__ acc,
                            int n_user4, int n_total4) {
    int i = blockIdx.x * blockDim.x + threadIdx.x;
    if (i >= n_total4) return;
    float4 v = (i < n_user4) ? ue[i] : ie[i - n_user4];
    cur[i] = v;
    acc[i] = v;
}

// Per-row edge counts.
__global__ void histo(const int* __restrict__ rows, int* __restrict__ counts,
                      int n_edges) {
    int e = blockIdx.x * blockDim.x + threadIdx.x;
    if (e < n_edges) atomicAdd(&counts[rows[e]], 1);
}

// --- hierarchical scan: reduce -> scan block sums -> final scan ---

__global__ void scan_reduce(const int* __restrict__ counts,
                            int* __restrict__ block_sums, int n) {
    __shared__ int red[1024];
    int tid = threadIdx.x;
    int i = blockIdx.x * 1024 + tid;
    red[tid] = (i < n) ? counts[i] : 0;
    __syncthreads();
    for (int d = 512; d > 0; d >>= 1) {
        if (tid < d) red[tid] += red[tid + d];
        __syncthreads();
    }
    if (tid == 0) block_sums[blockIdx.x] = red[0];
}

__global__ void scan_blocksums(int* __restrict__ block_sums, int nb) {
    __shared__ int s[1024];
    int tid = threadIdx.x;
    int v = (tid < nb) ? block_sums[tid] : 0;
    s[tid] = v;
    __syncthreads();
    for (int d = 1; d < 1024; d <<= 1) {
        int t = (tid >= d) ? s[tid - d] : 0;
        __syncthreads();
        s[tid] += t;
        __syncthreads();
    }
    if (tid < nb) block_sums[tid] = s[tid] - v;  // exclusive
}

// Writes row_start and rewrites counts[] in place as the fill cursors.
__global__ void scan_final(int* __restrict__ counts,
                           const int* __restrict__ block_sums,
                           int* __restrict__ row_start, int n) {
    __shared__ int s[1024];
    int tid = threadIdx.x;
    int i = blockIdx.x * 1024 + tid;
    int v = (i < n) ? counts[i] : 0;
    s[tid] = v;
    __syncthreads();
    for (int d = 1; d < 1024; d <<= 1) {
        int t = (tid >= d) ? s[tid - d] : 0;
        __syncthreads();
        s[tid] += t;
        __syncthreads();
    }
    int excl = s[tid] - v + block_sums[blockIdx.x];
    if (i < n) {
        row_start[i] = excl;
        counts[i] = excl;  // fill cursor
        if (i == n - 1) row_start[n] = excl + v;
    }
}

// bucket_cursor[b] = row_start[min(b<<BUCKET_SHIFT, n)] for b in [0, nb)
__global__ void init_cursors(const int* __restrict__ row_start,
                             int* __restrict__ bucket_cursor,
                             int n_nodes, int nb) {
    int b = blockIdx.x * blockDim.x + threadIdx.x;
    if (b >= nb) return;
    int r = b << BUCKET_SHIFT;
    if (r > n_nodes) r = n_nodes;
    bucket_cursor[b] = row_start[r];
}

// Pass 1: bucket-grouped append scatter with block-level LDS aggregation.
__global__ void build_pass1(const int* __restrict__ rows,
                            const int* __restrict__ cols,
                            const float* __restrict__ vals,
                            int* __restrict__ bucket_cursor,
                            int2* __restrict__ es_tmp,
                            int* __restrict__ row_tmp,
                            int n_edges, int nb) {
    __shared__ int cnt[256];
    __shared__ int base[256];
    int tid = threadIdx.x;
    int beg = blockIdx.x * EPB;
    int end = min(beg + EPB, n_edges);

    if (tid < nb) cnt[tid] = 0;
    __syncthreads();

    // Phase A: count per-bucket within this chunk
    for (int e = beg + tid; e < end; e += 256) {
        int b = rows[e] >> BUCKET_SHIFT;
        atomicAdd(&cnt[b], 1);
    }
    __syncthreads();

    // Phase B: reserve global ranges, reset local cursors
    if (tid < nb) {
        int c = cnt[tid];
        base[tid] = c ? atomicAdd(&bucket_cursor[tid], c) : 0;
        cnt[tid] = 0;
    }
    __syncthreads();

    // Phase C: place edges at the bucket frontiers (dense, line-friendly)
    for (int e = beg + tid; e < end; e += 256) {
        int r = rows[e];
        int b = r >> BUCKET_SHIFT;
        int pos = base[b] + atomicAdd(&cnt[b], 1);
        es_tmp[pos] = make_int2(cols[e], __float_as_int(vals[e]));
        row_tmp[pos] = r;
    }
}

// Pass 2: fine scatter within bucket windows (destination locality ~64KB).
__global__ void build_pass2(const int2* __restrict__ es_tmp,
                            const int* __restrict__ row_tmp,
                            int* __restrict__ fill,
                            int2* __restrict__ es, int n_edges) {
    int e = blockIdx.x * blockDim.x + threadIdx.x;
    if (e >= n_edges) return;
    int r = row_tmp[e];
    int pos = atomicAdd(&fill[r], 1);
    es[pos] = es_tmp[e];
}

// Row-parallel CSR SpMM, 16 lanes per row. Streaming traffic (es, y, acc)
// is non-temporal so the gather-hot x stays L2-resident. Fused epilogue:
// acc += y; last layer: acc = (acc + y) * 0.25, no y store.
__global__ void spmm_csr(const int* __restrict__ row_start,
                         const int2* __restrict__ es,
                         const float* __restrict__ x,
                         float* __restrict__ y,
                         float* __restrict__ acc,
                         int n_nodes, int last) {
    int gid = blockIdx.x * blockDim.x + threadIdx.x;
    int r = gid >> 4;
    if (r >= n_nodes) return;
    int q = gid & 15;
    int beg = row_start[r];
    int end = row_start[r + 1];
    const nt_i2* esv = (const nt_i2*)es;
    nt_f4 a = (nt_f4)(0.f);
    for (int j = beg; j < end; ++j) {
        nt_i2 e = __builtin_nontemporal_load(&esv[j]);
        float v = __int_as_float(e.y);
        nt_f4 xv = *(const nt_f4*)(x + (size_t)e.x * EMB + q * 4);
        a += v * xv;
    }
    size_t o = (size_t)r * EMB + q * 4;
    nt_f4 ac = __builtin_nontemporal_load((const nt_f4*)(acc + o));
    ac += a;
    if (last) {
        ac *= 0.25f;
    } else {
        __builtin_nontemporal_store(a, (nt_f4*)(y + o));
    }
    __builtin_nontemporal_store(ac, (nt_f4*)(acc + o));
}

extern "C" void kernel_launch(void* const* d_in, const int* in_sizes, int n_in,
                              void* d_out, int out_size, void* d_ws, size_t ws_size,
                              hipStream_t stream) {
    const float* ue   = (const float*)d_in[0];
    const float* ie   = (const float*)d_in[1];
    const int*   rows = (const int*)d_in[2];
    const int*   cols = (const int*)d_in[3];
    const float* vals = (const float*)d_in[4];
    float* out = (float*)d_out;

    const int num_users = in_sizes[0] / EMB;
    const int num_items = in_sizes[1] / EMB;
    const int n_nodes   = num_users + num_items;
    const int n_edges   = in_sizes[2];

    // Workspace layout (~87.6 MB):
    //  buf0, buf1 : ping-pong node embeddings (38.4 MB each)
    //               buf1 doubles as es_tmp+row_tmp during the build phase
    //               (14.4 MB <= 38.4 MB; build finishes before layer-1 spmm
    //               writes buf1 — same-stream ordering guarantees this)
    //  es         : row-grouped (col,val) pairs (9.6 MB)
    //  row_start  : n_nodes+1 ints
    //  counts/fill: n_nodes ints (histogram -> cursors)
    //  block_sums : scan partials
    //  bucket_cursor : per-bucket append cursors
    const size_t buf_elems = (size_t)n_nodes * EMB;
    float* buf0 = (float*)d_ws;
    float* buf1 = buf0 + buf_elems;
    int2*  es_tmp = (int2*)buf1;
    int*   row_tmp = (int*)(es_tmp + n_edges);
    int2*  es   = (int2*)(buf1 + buf_elems);
    int*   row_start  = (int*)(es + n_edges);
    int*   counts     = row_start + (n_nodes + 1);
    int*   block_sums = counts + n_nodes;
    int*   bucket_cursor = block_sums + 1024;

    const int n_total4 = n_nodes * (EMB / 4);
    const int n_user4  = num_users * (EMB / 4);
    const int nb_scan  = (n_nodes + 1023) / 1024;                // 147
    const int nb_bkt   = (n_nodes + (1 << BUCKET_SHIFT) - 1) >> BUCKET_SHIFT;

    // 0) zero the histogram
    (void)hipMemsetAsync(counts, 0, (size_t)n_nodes * sizeof(int), stream);

    // 1) concat inputs into cur buffer and accumulator (d_out)
    {
        int threads = 256;
        int blocks  = (n_total4 + threads - 1) / threads;
        concat_init<<<blocks, threads, 0, stream>>>(
            (const float4*)ue, (const float4*)ie,
            (float4*)buf0, (float4*)out, n_user4, n_total4);
    }

    // 2) build row-grouped edge list (histo -> scan -> 2-pass bucket scatter)
    {
        int threads = 256;
        int eblocks = (n_edges + threads - 1) / threads;
        histo<<<eblocks, threads, 0, stream>>>(rows, counts, n_edges);
        scan_reduce<<<nb_scan, 1024, 0, stream>>>(counts, block_sums, n_nodes);
        scan_blocksums<<<1, 1024, 0, stream>>>(block_sums, nb_scan);
        scan_final<<<nb_scan, 1024, 0, stream>>>(counts, block_sums,
                                                 row_start, n_nodes);
        init_cursors<<<(nb_bkt + 255) / 256, 256, 0, stream>>>(
            row_start, bucket_cursor, n_nodes, nb_bkt);
        build_pass1<<<(n_edges + EPB - 1) / EPB, 256, 0, stream>>>(
            rows, cols, vals, bucket_cursor, es_tmp, row_tmp, n_edges, nb_bkt);
        build_pass2<<<eblocks, threads, 0, stream>>>(
            es_tmp, row_tmp, counts, es, n_edges);
    }

    // 3) three propagation layers, acc update fused into SpMM epilogue
    float* cur = buf0;
    float* nxt = buf1;
    for (int layer = 0; layer < 3; ++layer) {
        int threads = 256;
        int blocks  = (n_nodes * 16 + threads - 1) / threads;
        spmm_csr<<<blocks, threads, 0, stream>>>(
            row_start, es, cur, nxt, out,
            n_nodes, layer == 2 ? 1 : 0);
        float* t = cur; cur = nxt; nxt = t;
    }
}